// Round 1
// baseline (681.441 us; speedup 1.0000x reference)
//
#include <hip/hip_runtime.h>
#include <cstdint>

#define B_ 8
#define T_ 4096
#define TP1 4097
#define IN_ 512
#define H_ 512
#define N3H 1536
#define KD 1024
#define CHUNKS 64
#define CLEN 64   // T_/CHUNKS

typedef __attribute__((ext_vector_type(4))) float floatx4;
typedef __attribute__((ext_vector_type(4))) float f4;
typedef __attribute__((ext_vector_type(8))) short short8;
typedef __attribute__((ext_vector_type(4))) unsigned short us4;

__device__ __forceinline__ unsigned short f2bf(float v){
  unsigned int u = __float_as_uint(v);
  unsigned int r = (u + 0x7fffu + ((u >> 16) & 1u)) >> 16;
  return (unsigned short)r;
}
__device__ __forceinline__ float sigm(float x){ return 1.f/(1.f + __expf(-x)); }
__device__ __forceinline__ float tanhf_(float x){ return 2.f*sigm(2.f*x) - 1.f; }

// x f32 [B,T,IN] -> xpad bf16 [B, T+1, IN] with zero row at t'=0 (causal pad)
__global__ void cast_pad_kernel(const float* __restrict__ x, unsigned short* __restrict__ xpad){
  int64_t i = (int64_t)blockIdx.x*256 + threadIdx.x;       // over B*TP1*(IN/4)
  const int64_t total = (int64_t)B_*TP1*(IN_/4);
  if (i >= total) return;
  int cg = (int)(i & 127);
  int64_t r = i >> 7;                                      // row (b*TP1 + t)
  int t = (int)(r % TP1);
  int b = (int)(r / TP1);
  us4 o;
  if (t == 0){ o = (us4){0,0,0,0}; }
  else {
    f4 v = *(const f4*)(x + ((int64_t)b*T_ + (t-1))*IN_ + cg*4);
    #pragma unroll
    for (int u=0;u<4;++u) o[u] = f2bf(v[u]);
  }
  *(us4*)(xpad + r*IN_ + cg*4) = o;
}

// w f32 [3H, IN, K=2] -> wt bf16 [3H, 1024] with k-major halves: wt[o][k*512+ci]
__global__ void wt_kernel(const float* __restrict__ w, unsigned short* __restrict__ wt){
  int i = blockIdx.x*256 + threadIdx.x;                    // over N3H*512
  if (i >= N3H*512) return;
  int ci = i & 511;
  int o = i >> 9;
  const float* wp = w + (int64_t)o*KD + ci*2;
  wt[(int64_t)o*KD + ci]       = f2bf(wp[0]);
  wt[(int64_t)o*KD + 512 + ci] = f2bf(wp[1]);
}

// C[m][n] = sum_k A[m][k]*W[n][k];  A row m at (m + m/T_)*512 in xpad, length 1024
__global__ __launch_bounds__(256) void gemm_kernel(
    const unsigned short* __restrict__ A, const unsigned short* __restrict__ W,
    float* __restrict__ C){
  __shared__ unsigned short As[128*32];
  __shared__ unsigned short Bs[128*32];
  const int tid = threadIdx.x;
  const int lane = tid & 63;
  const int wave = tid >> 6;
  const int m0 = blockIdx.y * 128;
  const int n0 = blockIdx.x * 128;
  const int bb = m0 / T_;                    // tile fully inside one batch (128 | 4096)
  // staging: chunk p=c*256+tid -> LDS bytes p*16; row r=p>>2, col (p&3)*8
  const unsigned short* aSrc = A + (int64_t)(m0 + bb + (tid>>2))*IN_ + (tid&3)*8;
  const unsigned short* bSrc = W + (int64_t)(n0 + (tid>>2))*KD + (tid&3)*8;
  unsigned short* aDst = As + tid*8;
  unsigned short* bDst = Bs + tid*8;
  const int wm = wave & 1;
  const int wn = wave >> 1;
  const int l16 = lane & 15;
  const int quad = lane >> 4;
  floatx4 acc[4][4];
  #pragma unroll
  for (int i=0;i<4;i++)
    #pragma unroll
    for (int j=0;j<4;j++) acc[i][j] = (floatx4){0.f,0.f,0.f,0.f};
  const unsigned short* aLds = As + (wm*64 + l16)*32 + quad*8;
  const unsigned short* bLds = Bs + (wn*64 + l16)*32 + quad*8;

  for (int kk = 0; kk < KD; kk += 32){
    __syncthreads();
    __builtin_amdgcn_global_load_lds((const __attribute__((address_space(1))) void*)(aSrc + kk),
                                     (__attribute__((address_space(3))) void*)(aDst), 16, 0, 0);
    __builtin_amdgcn_global_load_lds((const __attribute__((address_space(1))) void*)(aSrc + 64*IN_ + kk),
                                     (__attribute__((address_space(3))) void*)(aDst + 2048), 16, 0, 0);
    __builtin_amdgcn_global_load_lds((const __attribute__((address_space(1))) void*)(bSrc + kk),
                                     (__attribute__((address_space(3))) void*)(bDst), 16, 0, 0);
    __builtin_amdgcn_global_load_lds((const __attribute__((address_space(1))) void*)(bSrc + 64*KD + kk),
                                     (__attribute__((address_space(3))) void*)(bDst + 2048), 16, 0, 0);
    __syncthreads();
    short8 af[4], bfr[4];
    #pragma unroll
    for (int i=0;i<4;i++) af[i] = *(const short8*)(aLds + i*16*32);
    #pragma unroll
    for (int j=0;j<4;j++) bfr[j] = *(const short8*)(bLds + j*16*32);
    #pragma unroll
    for (int i=0;i<4;i++)
      #pragma unroll
      for (int j=0;j<4;j++)
        acc[i][j] = __builtin_amdgcn_mfma_f32_16x16x32_bf16(af[i], bfr[j], acc[i][j], 0, 0, 0);
  }
  #pragma unroll
  for (int i=0;i<4;i++){
    int row = m0 + wm*64 + i*16 + quad*4;
    #pragma unroll
    for (int j=0;j<4;j++){
      int col = n0 + wn*64 + j*16 + l16;
      float* cp = C + (int64_t)row*N3H + col;
      #pragma unroll
      for (int r=0;r<4;r++) cp[(int64_t)r*N3H] = acc[i][j][r];
    }
  }
}

// phase 1: per-chunk affine composition (Aa, Bb): h_out = Aa*h_in + Bb
__global__ void scan_phase1(const float* __restrict__ conv, const float* __restrict__ bias,
                            float* __restrict__ carA, float* __restrict__ carB){
  int q = blockIdx.x*256 + threadIdx.x;     // 65536 = 64 chunks * 8 b * 128 ch-groups
  int chg = q & 127;
  int bq = (q >> 7) & 7;
  int c  = q >> 10;
  int ch = chg*4;
  f4 bz = *(const f4*)(bias + ch);
  f4 bf = *(const f4*)(bias + 512 + ch);
  f4 Aa = {1.f,1.f,1.f,1.f}, Bb = {0.f,0.f,0.f,0.f};
  const float* p = conv + ((int64_t)bq*T_ + c*CLEN)*N3H + ch;
  for (int s=0;s<CLEN;++s){
    f4 zr = *(const f4*)p;
    f4 fr = *(const f4*)(p+512);
    #pragma unroll
    for (int u=0;u<4;++u){
      float fv = sigm(fr[u] + bf[u]);
      float zv = tanhf_(zr[u] + bz[u]);
      Aa[u] *= fv;
      Bb[u] = fv*Bb[u] + (1.f-fv)*zv;
    }
    p += N3H;
  }
  *(f4*)(carA + (int64_t)q*4) = Aa;
  *(f4*)(carB + (int64_t)q*4) = Bb;
}

// phase 2: scan over chunks; emit h at chunk starts + final hT
__global__ void scan_phase2(const float* __restrict__ carA, const float* __restrict__ carB,
                            float* __restrict__ hstart, float* __restrict__ hT){
  int q = blockIdx.x*256 + threadIdx.x;     // 1024 (4 channels each)
  f4 h = {0.f,0.f,0.f,0.f};
  for (int c=0;c<CHUNKS;++c){
    int64_t idx = (int64_t)c*4096 + q*4;
    *(f4*)(hstart + idx) = h;
    f4 a = *(const f4*)(carA + idx);
    f4 b = *(const f4*)(carB + idx);
    #pragma unroll
    for (int u=0;u<4;++u) h[u] = a[u]*h[u] + b[u];
  }
  *(f4*)(hT + (int64_t)q*4) = h;
}

// phase 3: replay chunk with true h-start, apply o*h, write output
template<int LAYER>
__global__ void scan_phase3(const float* __restrict__ conv, const float* __restrict__ bias,
                            const float* __restrict__ hstart, unsigned short* __restrict__ xpad,
                            float* __restrict__ outf){
  int q = blockIdx.x*256 + threadIdx.x;     // 65536
  int chg = q & 127;
  int bq = (q >> 7) & 7;
  int c  = q >> 10;
  int ch = chg*4;
  f4 bz = *(const f4*)(bias + ch);
  f4 bf = *(const f4*)(bias + 512 + ch);
  f4 bo = *(const f4*)(bias + 1024 + ch);
  f4 h = *(const f4*)(hstart + (int64_t)q*4);
  const float* p = conv + ((int64_t)bq*T_ + c*CLEN)*N3H + ch;
  int t = c*CLEN;
  for (int s=0;s<CLEN;++s){
    f4 zr = *(const f4*)p;
    f4 fr = *(const f4*)(p+512);
    f4 orr = *(const f4*)(p+1024);
    if (LAYER == 0){
      us4 ov4;
      #pragma unroll
      for (int u=0;u<4;++u){
        float fv = sigm(fr[u] + bf[u]);
        float zv = tanhf_(zr[u] + bz[u]);
        float ov = sigm(orr[u] + bo[u]);
        h[u] = fv*h[u] + (1.f-fv)*zv;
        ov4[u] = f2bf(ov*h[u]);
      }
      *(us4*)(xpad + ((int64_t)bq*TP1 + t + 1)*IN_ + ch) = ov4;
    } else {
      f4 of4;
      #pragma unroll
      for (int u=0;u<4;++u){
        float fv = sigm(fr[u] + bf[u]);
        float zv = tanhf_(zr[u] + bz[u]);
        float ov = sigm(orr[u] + bo[u]);
        h[u] = fv*h[u] + (1.f-fv)*zv;
        of4[u] = ov*h[u];
      }
      *(f4*)(outf + ((int64_t)bq*T_ + t)*H_ + ch) = of4;
    }
    ++t; p += N3H;
  }
}

extern "C" void kernel_launch(void* const* d_in, const int* in_sizes, int n_in,
                              void* d_out, int out_size, void* d_ws, size_t ws_size,
                              hipStream_t stream){
  const float* x  = (const float*)d_in[0];
  const float* w0 = (const float*)d_in[1];
  const float* b0 = (const float*)d_in[2];
  const float* w1 = (const float*)d_in[3];
  const float* b1 = (const float*)d_in[4];
  float* out = (float*)d_out;

  char* ws = (char*)d_ws;
  size_t off = 0;
  auto alloc = [&](size_t bytes)->char*{
    char* p = ws + off; off = (off + bytes + 255) & ~(size_t)255; return p; };
  unsigned short* xpad = (unsigned short*)alloc((size_t)B_*TP1*IN_*2);
  unsigned short* Wt0  = (unsigned short*)alloc((size_t)N3H*KD*2);
  unsigned short* Wt1  = (unsigned short*)alloc((size_t)N3H*KD*2);
  float* conv = (float*)alloc((size_t)B_*T_*N3H*4);
  float* carA = (float*)alloc((size_t)CHUNKS*4096*4);
  float* carB = (float*)alloc((size_t)CHUNKS*4096*4);
  float* hst  = (float*)alloc((size_t)CHUNKS*4096*4);
  if (off > ws_size) return;  // workspace too small -> fail loudly in validation

  float* out_main = out;
  float* h0 = out + (int64_t)B_*T_*H_;
  float* h1 = h0 + B_*H_;

  const int64_t padN = (int64_t)B_*TP1*(IN_/4);
  cast_pad_kernel<<<(int)((padN + 255)/256), 256, 0, stream>>>(x, xpad);
  wt_kernel<<<(N3H*512 + 255)/256, 256, 0, stream>>>(w0, Wt0);
  wt_kernel<<<(N3H*512 + 255)/256, 256, 0, stream>>>(w1, Wt1);

  dim3 ggrid(N3H/128, (B_*T_)/128);
  gemm_kernel<<<ggrid, 256, 0, stream>>>(xpad, Wt0, conv);
  scan_phase1<<<256, 256, 0, stream>>>(conv, b0, carA, carB);
  scan_phase2<<<4, 256, 0, stream>>>(carA, carB, hst, h0);
  scan_phase3<0><<<256, 256, 0, stream>>>(conv, b0, hst, xpad, nullptr);

  gemm_kernel<<<ggrid, 256, 0, stream>>>(xpad, Wt1, conv);
  scan_phase1<<<256, 256, 0, stream>>>(conv, b1, carA, carB);
  scan_phase2<<<4, 256, 0, stream>>>(carA, carB, hst, h1);
  scan_phase3<1><<<256, 256, 0, stream>>>(conv, b1, hst, nullptr, out_main);
}

// Round 2
// 491.172 us; speedup vs baseline: 1.3874x; 1.3874x over previous
//
#include <hip/hip_runtime.h>
#include <cstdint>

#define B_ 8
#define T_ 4096
#define TP1 4097
#define IN_ 512
#define H_ 512
#define N3H 1536
#define KD 1024
#define CHUNKS 64
#define CLEN 64   // T_/CHUNKS

typedef __attribute__((ext_vector_type(4))) float floatx4;
typedef __attribute__((ext_vector_type(4))) float f4;
typedef __attribute__((ext_vector_type(8))) short short8;
typedef __attribute__((ext_vector_type(4))) unsigned short us4;
typedef __attribute__((ext_vector_type(4))) _Float16 h4;

__device__ __forceinline__ unsigned short f2bf(float v){
  unsigned int u = __float_as_uint(v);
  unsigned int r = (u + 0x7fffu + ((u >> 16) & 1u)) >> 16;
  return (unsigned short)r;
}
__device__ __forceinline__ float sigm(float x){ return 1.f/(1.f + __expf(-x)); }
__device__ __forceinline__ float tanhf_(float x){ return 2.f*sigm(2.f*x) - 1.f; }

// x f32 [B,T,IN] -> xpad bf16 [B, T+1, IN] with zero row at t'=0 (causal pad)
__global__ void cast_pad_kernel(const float* __restrict__ x, unsigned short* __restrict__ xpad){
  int64_t i = (int64_t)blockIdx.x*256 + threadIdx.x;       // over B*TP1*(IN/4)
  const int64_t total = (int64_t)B_*TP1*(IN_/4);
  if (i >= total) return;
  int cg = (int)(i & 127);
  int64_t r = i >> 7;                                      // row (b*TP1 + t)
  int t = (int)(r % TP1);
  int b = (int)(r / TP1);
  us4 o;
  if (t == 0){ o = (us4){0,0,0,0}; }
  else {
    f4 v = *(const f4*)(x + ((int64_t)b*T_ + (t-1))*IN_ + cg*4);
    #pragma unroll
    for (int u=0;u<4;++u) o[u] = f2bf(v[u]);
  }
  *(us4*)(xpad + r*IN_ + cg*4) = o;
}

// w f32 [3H, IN, K=2] -> wt bf16 [3H, 1024] with k-major halves: wt[o][k*512+ci]
__global__ void wt_kernel(const float* __restrict__ w, unsigned short* __restrict__ wt){
  int i = blockIdx.x*256 + threadIdx.x;                    // over N3H*512
  if (i >= N3H*512) return;
  int ci = i & 511;
  int o = i >> 9;
  const float* wp = w + (int64_t)o*KD + ci*2;
  wt[(int64_t)o*KD + ci]       = f2bf(wp[0]);
  wt[(int64_t)o*KD + 512 + ci] = f2bf(wp[1]);
}

// C[m][n] = act(sum_k A[m][k]*W[n][k] + bias[n]) stored f16.
// XCD-swizzled linear grid: 12 col-tiles of a row-tile stay on one XCD.
__global__ __launch_bounds__(256) void gemm_kernel(
    const unsigned short* __restrict__ A, const unsigned short* __restrict__ W,
    const float* __restrict__ bias, _Float16* __restrict__ C){
  __shared__ unsigned short As[128*32];
  __shared__ unsigned short Bs[128*32];
  const int tid = threadIdx.x;
  const int lane = tid & 63;
  const int wave = tid >> 6;
  const int bid = blockIdx.x;
  const int xcd = bid & 7;
  const int kb  = bid >> 3;              // 0..383
  const int colt = kb % 12;
  const int rowt = (kb / 12) * 8 + xcd;  // 0..255
  const int m0 = rowt * 128;
  const int n0 = colt * 128;
  const int bb = m0 / T_;                // tile fully inside one batch (128 | 4096)
  const int act = n0 >> 9;               // 0=z(tanh), 1=f(sigm), 2=o(sigm)
  // staging: chunk p=tid -> LDS bytes p*16; row r=p>>2, col (p&3)*8
  const unsigned short* aSrc = A + (int64_t)(m0 + bb + (tid>>2))*IN_ + (tid&3)*8;
  const unsigned short* bSrc = W + (int64_t)(n0 + (tid>>2))*KD + (tid&3)*8;
  unsigned short* aDst = As + tid*8;
  unsigned short* bDst = Bs + tid*8;
  const int wm = wave & 1;
  const int wn = wave >> 1;
  const int l16 = lane & 15;
  const int quad = lane >> 4;
  floatx4 acc[4][4];
  #pragma unroll
  for (int i=0;i<4;i++)
    #pragma unroll
    for (int j=0;j<4;j++) acc[i][j] = (floatx4){0.f,0.f,0.f,0.f};
  const unsigned short* aLds = As + (wm*64 + l16)*32 + quad*8;
  const unsigned short* bLds = Bs + (wn*64 + l16)*32 + quad*8;

  for (int kk = 0; kk < KD; kk += 32){
    __syncthreads();
    __builtin_amdgcn_global_load_lds((const __attribute__((address_space(1))) void*)(aSrc + kk),
                                     (__attribute__((address_space(3))) void*)(aDst), 16, 0, 0);
    __builtin_amdgcn_global_load_lds((const __attribute__((address_space(1))) void*)(aSrc + 64*IN_ + kk),
                                     (__attribute__((address_space(3))) void*)(aDst + 2048), 16, 0, 0);
    __builtin_amdgcn_global_load_lds((const __attribute__((address_space(1))) void*)(bSrc + kk),
                                     (__attribute__((address_space(3))) void*)(bDst), 16, 0, 0);
    __builtin_amdgcn_global_load_lds((const __attribute__((address_space(1))) void*)(bSrc + 64*KD + kk),
                                     (__attribute__((address_space(3))) void*)(bDst + 2048), 16, 0, 0);
    __syncthreads();
    short8 af[4], bfr[4];
    #pragma unroll
    for (int i=0;i<4;i++) af[i] = *(const short8*)(aLds + i*16*32);
    #pragma unroll
    for (int j=0;j<4;j++) bfr[j] = *(const short8*)(bLds + j*16*32);
    #pragma unroll
    for (int i=0;i<4;i++)
      #pragma unroll
      for (int j=0;j<4;j++)
        acc[i][j] = __builtin_amdgcn_mfma_f32_16x16x32_bf16(af[i], bfr[j], acc[i][j], 0, 0, 0);
  }
  float bv[4];
  #pragma unroll
  for (int j=0;j<4;j++) bv[j] = bias[n0 + wn*64 + j*16 + l16];
  #pragma unroll
  for (int i=0;i<4;i++){
    int row = m0 + wm*64 + i*16 + quad*4;
    #pragma unroll
    for (int j=0;j<4;j++){
      int col = n0 + wn*64 + j*16 + l16;
      _Float16* cp = C + (int64_t)row*N3H + col;
      #pragma unroll
      for (int r=0;r<4;r++){
        float v = acc[i][j][r] + bv[j];
        v = (act == 0) ? tanhf_(v) : sigm(v);
        cp[(int64_t)r*N3H] = (_Float16)v;
      }
    }
  }
}

// phase 1: per-chunk affine composition (Aa, Bb): h_out = Aa*h_in + Bb
__global__ void scan_phase1(const _Float16* __restrict__ conv,
                            float* __restrict__ carA, float* __restrict__ carB){
  int q = blockIdx.x*256 + threadIdx.x;     // 65536 = 64 chunks * 8 b * 128 ch-groups
  int chg = q & 127;
  int bq = (q >> 7) & 7;
  int c  = q >> 10;
  int ch = chg*4;
  f4 Aa = {1.f,1.f,1.f,1.f}, Bb = {0.f,0.f,0.f,0.f};
  const _Float16* p = conv + ((int64_t)bq*T_ + c*CLEN)*N3H + ch;
  for (int s=0;s<CLEN;++s){
    h4 zh = *(const h4*)p;
    h4 fh = *(const h4*)(p+512);
    #pragma unroll
    for (int u=0;u<4;++u){
      float fv = (float)fh[u];
      float zv = (float)zh[u];
      Aa[u] *= fv;
      Bb[u] = fv*Bb[u] + (1.f-fv)*zv;
    }
    p += N3H;
  }
  *(f4*)(carA + (int64_t)q*4) = Aa;
  *(f4*)(carB + (int64_t)q*4) = Bb;
}

// phase 2: scan over chunks; emit h at chunk starts + final hT
__global__ void scan_phase2(const float* __restrict__ carA, const float* __restrict__ carB,
                            float* __restrict__ hstart, float* __restrict__ hT){
  int q = blockIdx.x*256 + threadIdx.x;     // 1024 (4 channels each)
  f4 h = {0.f,0.f,0.f,0.f};
  for (int c=0;c<CHUNKS;++c){
    int64_t idx = (int64_t)c*4096 + q*4;
    *(f4*)(hstart + idx) = h;
    f4 a = *(const f4*)(carA + idx);
    f4 b = *(const f4*)(carB + idx);
    #pragma unroll
    for (int u=0;u<4;++u) h[u] = a[u]*h[u] + b[u];
  }
  *(f4*)(hT + (int64_t)q*4) = h;
}

// phase 3: replay chunk with true h-start, apply o*h, write output
template<int LAYER>
__global__ void scan_phase3(const _Float16* __restrict__ conv,
                            const float* __restrict__ hstart, unsigned short* __restrict__ xpad,
                            float* __restrict__ outf){
  int q = blockIdx.x*256 + threadIdx.x;     // 65536
  int chg = q & 127;
  int bq = (q >> 7) & 7;
  int c  = q >> 10;
  int ch = chg*4;
  f4 h = *(const f4*)(hstart + (int64_t)q*4);
  const _Float16* p = conv + ((int64_t)bq*T_ + c*CLEN)*N3H + ch;
  int t = c*CLEN;
  for (int s=0;s<CLEN;++s){
    h4 zh = *(const h4*)p;
    h4 fh = *(const h4*)(p+512);
    h4 oh = *(const h4*)(p+1024);
    if (LAYER == 0){
      us4 ov4;
      #pragma unroll
      for (int u=0;u<4;++u){
        float fv = (float)fh[u];
        h[u] = fv*h[u] + (1.f-fv)*(float)zh[u];
        ov4[u] = f2bf((float)oh[u]*h[u]);
      }
      *(us4*)(xpad + ((int64_t)bq*TP1 + t + 1)*IN_ + ch) = ov4;
    } else {
      f4 of4;
      #pragma unroll
      for (int u=0;u<4;++u){
        float fv = (float)fh[u];
        h[u] = fv*h[u] + (1.f-fv)*(float)zh[u];
        of4[u] = (float)oh[u]*h[u];
      }
      *(f4*)(outf + ((int64_t)bq*T_ + t)*H_ + ch) = of4;
    }
    ++t; p += N3H;
  }
}

extern "C" void kernel_launch(void* const* d_in, const int* in_sizes, int n_in,
                              void* d_out, int out_size, void* d_ws, size_t ws_size,
                              hipStream_t stream){
  const float* x  = (const float*)d_in[0];
  const float* w0 = (const float*)d_in[1];
  const float* b0 = (const float*)d_in[2];
  const float* w1 = (const float*)d_in[3];
  const float* b1 = (const float*)d_in[4];
  float* out = (float*)d_out;

  char* ws = (char*)d_ws;
  size_t off = 0;
  auto alloc = [&](size_t bytes)->char*{
    char* p = ws + off; off = (off + bytes + 255) & ~(size_t)255; return p; };
  unsigned short* xpad = (unsigned short*)alloc((size_t)B_*TP1*IN_*2);
  unsigned short* Wt0  = (unsigned short*)alloc((size_t)N3H*KD*2);
  unsigned short* Wt1  = (unsigned short*)alloc((size_t)N3H*KD*2);
  _Float16* conv = (_Float16*)alloc((size_t)B_*T_*N3H*2);
  float* carA = (float*)alloc((size_t)CHUNKS*4096*4);
  float* carB = (float*)alloc((size_t)CHUNKS*4096*4);
  float* hst  = (float*)alloc((size_t)CHUNKS*4096*4);
  if (off > ws_size) return;  // workspace too small -> fail loudly in validation

  float* out_main = out;
  float* h0 = out + (int64_t)B_*T_*H_;
  float* h1 = h0 + B_*H_;

  const int64_t padN = (int64_t)B_*TP1*(IN_/4);
  cast_pad_kernel<<<(int)((padN + 255)/256), 256, 0, stream>>>(x, xpad);
  wt_kernel<<<(N3H*512 + 255)/256, 256, 0, stream>>>(w0, Wt0);
  wt_kernel<<<(N3H*512 + 255)/256, 256, 0, stream>>>(w1, Wt1);

  const int ggrid = (N3H/128) * ((B_*T_)/128);   // 3072
  gemm_kernel<<<ggrid, 256, 0, stream>>>(xpad, Wt0, b0, conv);
  scan_phase1<<<256, 256, 0, stream>>>(conv, carA, carB);
  scan_phase2<<<4, 256, 0, stream>>>(carA, carB, hst, h0);
  scan_phase3<0><<<256, 256, 0, stream>>>(conv, hst, xpad, nullptr);

  gemm_kernel<<<ggrid, 256, 0, stream>>>(xpad, Wt1, b1, conv);
  scan_phase1<<<256, 256, 0, stream>>>(conv, carA, carB);
  scan_phase2<<<4, 256, 0, stream>>>(carA, carB, hst, h1);
  scan_phase3<1><<<256, 256, 0, stream>>>(conv, hst, nullptr, out_main);
}